// Round 1
// baseline (375.040 us; speedup 1.0000x reference)
//
#include <hip/hip_runtime.h>
#include <hip/hip_bf16.h>
#include <stdint.h>

#define N_TOK   8192
#define DDIM    1024
#define HDIM    2048
#define NEXP    8
#define TOPK    2
#define NSLOTS  (N_TOK * TOPK)

typedef float f32x4 __attribute__((ext_vector_type(4)));
typedef __bf16 b16x8 __attribute__((ext_vector_type(8)));

__device__ __forceinline__ unsigned short f2bf(float f) {
  union { float f; uint32_t u; } x; x.f = f;
  uint32_t r = (x.u + 0x7FFFu + ((x.u >> 16) & 1u)) >> 16;
  return (unsigned short)r;
}
__device__ __forceinline__ float bf2f(unsigned short u) {
  union { uint32_t u; float f; } x; x.u = ((uint32_t)u) << 16; return x.f;
}

#define GLD16(gp, lp) __builtin_amdgcn_global_load_lds( \
    (const __attribute__((address_space(1))) void*)(gp), \
    (__attribute__((address_space(3))) void*)(lp), 16, 0, 0)

// ---------------- routing ----------------
__global__ void k_init(int* counts) {
  int i = threadIdx.x;
  if (i < NEXP) counts[i] = 0;
}
__global__ void k_count(const int* __restrict__ idx, int* __restrict__ counts) {
  int s = blockIdx.x * 256 + threadIdx.x;
  if (s < NSLOTS) atomicAdd(&counts[idx[s]], 1);
}
__global__ void k_scan(const int* __restrict__ counts, int* __restrict__ offsets,
                       int* __restrict__ cursor) {
  if (threadIdx.x == 0) {
    int o = 0;
    for (int e = 0; e < NEXP; ++e) { offsets[e] = o; cursor[e] = o; o += counts[e]; }
  }
}
__global__ void k_scatter(const int* __restrict__ idx, int* __restrict__ cursor,
                          int* __restrict__ slot_of_pos, int* __restrict__ pos_of_slot) {
  int s = blockIdx.x * 256 + threadIdx.x;
  if (s < NSLOTS) {
    int e = idx[s];
    int p = atomicAdd(&cursor[e], 1);
    slot_of_pos[p] = s;
    pos_of_slot[s] = p;
  }
}

// ---------------- fp32 -> bf16 conversion ----------------
__global__ void k_cvt(const float* __restrict__ src, unsigned short* __restrict__ dst, int n8) {
  int stride = gridDim.x * blockDim.x;
  for (int i = blockIdx.x * blockDim.x + threadIdx.x; i < n8; i += stride) {
    float4 a = ((const float4*)src)[2 * i];
    float4 b = ((const float4*)src)[2 * i + 1];
    union { unsigned short u[8]; uint4 v; } o;
    o.u[0] = f2bf(a.x); o.u[1] = f2bf(a.y); o.u[2] = f2bf(a.z); o.u[3] = f2bf(a.w);
    o.u[4] = f2bf(b.x); o.u[5] = f2bf(b.y); o.u[6] = f2bf(b.z); o.u[7] = f2bf(b.w);
    ((uint4*)dst)[i] = o.v;
  }
}

// ---------------- grouped GEMM (NT): C[r, c] = A[r, :K] . B[c, :K] ----------------
// 128x128 tile, BK=64, 4 waves, each wave 64x64 (4x4 frags of 16x16x32 bf16).
// LDS tiles [128 rows][64 k] bf16 (128 B rows), XOR-swizzled byte^((row&7)<<4),
// staged via global_load_lds with the inverse swizzle applied to the GLOBAL source
// (rule #21: linear LDS dest, pre-swizzled source, swizzled ds_read).
template<int K, int NCOLS, bool GATHER, bool RELU2>
__global__ __launch_bounds__(256, 2)
void k_gemm(const unsigned short* __restrict__ A,
            const unsigned short* __restrict__ B,
            unsigned short* __restrict__ C,
            const int* __restrict__ counts,
            const int* __restrict__ offsets,
            const int* __restrict__ slot_of_pos)
{
  const int e   = blockIdx.z;
  const int cnt = counts[e];
  const int rt  = blockIdx.y;
  if (rt * 128 >= cnt) return;
  const int ct  = blockIdx.x;
  const int off = offsets[e];

  __shared__ unsigned short ldsA[128 * 64];
  __shared__ unsigned short ldsB[128 * 64];

  const int t    = threadIdx.x;
  const int lane = t & 63;
  const int wid  = t >> 6;

  const unsigned short* Bexp = B + (size_t)e * NCOLS * K;

  // staging: 16 chunks of 1 KiB; chunk = j*4 + wid; lane covers bytes chunk*1024 + lane*16
  const unsigned short* aSrc[4];
  const unsigned short* bSrc[4];
  unsigned short* aDst[4];
  unsigned short* bDst[4];
#pragma unroll
  for (int j = 0; j < 4; ++j) {
    const int chunk = j * 4 + wid;                 // 0..15 (wave-uniform per call)
    const int row   = chunk * 8 + (lane >> 3);     // LDS row 0..127
    const int qcol  = ((lane & 7) * 16) ^ ((row & 7) << 4);  // pre-swizzled logical byte
    int pr  = rt * 128 + row;
    int prc = pr < cnt ? pr : 0;
    if constexpr (GATHER) {
      int tok = slot_of_pos[off + prc] >> 1;       // slot -> token (K=2)
      aSrc[j] = A + (size_t)tok * K + (qcol >> 1);
    } else {
      aSrc[j] = A + (size_t)(off + prc) * K + (qcol >> 1);
    }
    bSrc[j] = Bexp + (size_t)(ct * 128 + row) * K + (qcol >> 1);
    aDst[j] = ldsA + chunk * 512;                  // 1024 B / 2
    bDst[j] = ldsB + chunk * 512;
  }

  f32x4 acc[4][4];
#pragma unroll
  for (int m = 0; m < 4; ++m)
#pragma unroll
    for (int n = 0; n < 4; ++n) acc[m][n] = (f32x4){0.f, 0.f, 0.f, 0.f};

  const int wr = wid >> 1, wc = wid & 1;
  const int kq = (lane >> 4) * 16;                 // byte offset of this lane's k-chunk
  int aByte[4], bByte[4], aXor[4], bXor[4];
#pragma unroll
  for (int m = 0; m < 4; ++m) {
    int row = wr * 64 + m * 16 + (lane & 15);
    aByte[m] = row * 128; aXor[m] = (row & 7) << 4;
    int col = wc * 64 + m * 16 + (lane & 15);
    bByte[m] = col * 128; bXor[m] = (col & 7) << 4;
  }

  for (int kt = 0; kt < K / 64; ++kt) {
#pragma unroll
    for (int j = 0; j < 4; ++j) {
      GLD16(aSrc[j] + kt * 64, aDst[j]);
      GLD16(bSrc[j] + kt * 64, bDst[j]);
    }
    __syncthreads();
#pragma unroll
    for (int ks = 0; ks < 2; ++ks) {
      b16x8 af[4], bfr[4];
#pragma unroll
      for (int m = 0; m < 4; ++m) {
        af[m]  = *(const b16x8*)((const char*)ldsA + aByte[m] + (((ks * 64) + kq) ^ aXor[m]));
        bfr[m] = *(const b16x8*)((const char*)ldsB + bByte[m] + (((ks * 64) + kq) ^ bXor[m]));
      }
#pragma unroll
      for (int m = 0; m < 4; ++m)
#pragma unroll
        for (int n = 0; n < 4; ++n)
          acc[m][n] = __builtin_amdgcn_mfma_f32_16x16x32_bf16(af[m], bfr[n], acc[m][n], 0, 0, 0);
    }
    __syncthreads();
  }

  // epilogue: C/D layout col = lane&15, row = (lane>>4)*4 + r  (m89-verified)
  const int rbase = rt * 128 + wr * 64 + (lane >> 4) * 4;
  const int cbase = ct * 128 + wc * 64 + (lane & 15);
#pragma unroll
  for (int m = 0; m < 4; ++m) {
#pragma unroll
    for (int r = 0; r < 4; ++r) {
      int pr = rbase + m * 16 + r;
      if (pr < cnt) {
        unsigned short* crow = C + (size_t)(off + pr) * NCOLS + cbase;
#pragma unroll
        for (int n = 0; n < 4; ++n) {
          float v = acc[m][n][r];
          if (RELU2) v = v > 0.f ? v * v : 0.f;
          crow[n * 16] = f2bf(v);
        }
      }
    }
  }
}

// ---------------- weighted combine of the two slots per token ----------------
__global__ void k_combine(const unsigned short* __restrict__ oslt,
                          const int* __restrict__ pos_of_slot,
                          const float* __restrict__ ew,
                          float* __restrict__ out)
{
  int n = blockIdx.x;
  int d = threadIdx.x * 4;
  int p0 = pos_of_slot[2 * n];
  int p1 = pos_of_slot[2 * n + 1];
  float w0 = ew[2 * n], w1 = ew[2 * n + 1];
  ushort4 a = *(const ushort4*)(oslt + (size_t)p0 * DDIM + d);
  ushort4 b = *(const ushort4*)(oslt + (size_t)p1 * DDIM + d);
  float4 o;
  o.x = w0 * bf2f(a.x) + w1 * bf2f(b.x);
  o.y = w0 * bf2f(a.y) + w1 * bf2f(b.y);
  o.z = w0 * bf2f(a.z) + w1 * bf2f(b.z);
  o.w = w0 * bf2f(a.w) + w1 * bf2f(b.w);
  *(float4*)(out + (size_t)n * DDIM + d) = o;
}

extern "C" void kernel_launch(void* const* d_in, const int* in_sizes, int n_in,
                              void* d_out, int out_size, void* d_ws, size_t ws_size,
                              hipStream_t stream)
{
  const float* x  = (const float*)d_in[0];
  const int* eidx = (const int*)d_in[1];
  const float* ew = (const float*)d_in[2];
  const float* w1 = (const float*)d_in[3];
  const float* w2 = (const float*)d_in[4];
  float* out = (float*)d_out;

  char* ws = (char*)d_ws;
  // layout (bytes):
  //   [0,            16777216)  xb   (8192x1024 bf16)          } dead after up-GEMM
  //   [16777216,     50331648)  w1b  (8x2048x1024 bf16)        }
  //   [0,            33554432)  oslt (16384x1024 bf16)  -- aliases xb+w1b, live after up-GEMM
  //   [50331648,     83886080)  w2b  (8x1024x2048 bf16)
  //   [83886080,    150994944)  hid  (16384x2048 bf16)
  //   [150994944,  ...       )  routing ints
  unsigned short* xb   = (unsigned short*)ws;
  unsigned short* w1b  = (unsigned short*)(ws + (size_t)16777216);
  unsigned short* oslt = (unsigned short*)ws;
  unsigned short* w2b  = (unsigned short*)(ws + (size_t)50331648);
  unsigned short* hid  = (unsigned short*)(ws + (size_t)83886080);
  int* counts      = (int*)(ws + (size_t)150994944);
  int* offsets     = counts + NEXP;
  int* cursor      = offsets + NEXP;
  int* slot_of_pos = cursor + NEXP;
  int* pos_of_slot = slot_of_pos + NSLOTS;

  k_init<<<1, 64, 0, stream>>>(counts);
  k_count<<<NSLOTS / 256, 256, 0, stream>>>(eidx, counts);
  k_scan<<<1, 64, 0, stream>>>(counts, offsets, cursor);
  k_scatter<<<NSLOTS / 256, 256, 0, stream>>>(eidx, cursor, slot_of_pos, pos_of_slot);

  k_cvt<<<2048, 256, 0, stream>>>(x,  xb,  N_TOK * DDIM / 8);
  k_cvt<<<2048, 256, 0, stream>>>(w1, w1b, NEXP * HDIM * DDIM / 8);
  k_cvt<<<2048, 256, 0, stream>>>(w2, w2b, NEXP * DDIM * HDIM / 8);

  dim3 gup(HDIM / 128, 128, NEXP);   // col tiles, max row tiles, experts
  k_gemm<DDIM, HDIM, true,  true ><<<gup, 256, 0, stream>>>(xb,  w1b, hid,  counts, offsets, slot_of_pos);
  dim3 gdn(DDIM / 128, 128, NEXP);
  k_gemm<HDIM, DDIM, false, false><<<gdn, 256, 0, stream>>>(hid, w2b, oslt, counts, offsets, slot_of_pos);

  k_combine<<<N_TOK, 256, 0, stream>>>(oslt, pos_of_slot, ew, out);
}

// Round 2
// 252.049 us; speedup vs baseline: 1.4880x; 1.4880x over previous
//
#include <hip/hip_runtime.h>
#include <hip/hip_bf16.h>
#include <stdint.h>

#define N_TOK   8192
#define DDIM    1024
#define HDIM    2048
#define NEXP    8
#define TOPK    2
#define NSLOTS  (N_TOK * TOPK)

typedef float f32x4 __attribute__((ext_vector_type(4)));
typedef __bf16 b16x8 __attribute__((ext_vector_type(8)));

__device__ __forceinline__ unsigned short f2bf(float f) {
  union { float f; uint32_t u; } x; x.f = f;
  uint32_t r = (x.u + 0x7FFFu + ((x.u >> 16) & 1u)) >> 16;
  return (unsigned short)r;
}
__device__ __forceinline__ float bf2f(unsigned short u) {
  union { uint32_t u; float f; } x; x.u = ((uint32_t)u) << 16; return x.f;
}

#define GLD16(gp, lp) __builtin_amdgcn_global_load_lds( \
    (const __attribute__((address_space(1))) void*)(gp), \
    (__attribute__((address_space(3))) void*)(lp), 16, 0, 0)

// ---------------- routing: one block does count + scan + scatter ----------------
__global__ void k_route(const int* __restrict__ idx, int* __restrict__ counts,
                        int* __restrict__ offsets,
                        int* __restrict__ slot_of_pos, int* __restrict__ pos_of_slot) {
  __shared__ int sc[NEXP], so[NEXP], scur[NEXP];
  int t = threadIdx.x;
  if (t < NEXP) sc[t] = 0;
  __syncthreads();
  for (int s = t; s < NSLOTS; s += 1024) atomicAdd(&sc[idx[s]], 1);
  __syncthreads();
  if (t == 0) {
    int o = 0;
    for (int e = 0; e < NEXP; ++e) { so[e] = o; scur[e] = o; o += sc[e]; }
  }
  __syncthreads();
  for (int s = t; s < NSLOTS; s += 1024) {
    int e = idx[s];
    int p = atomicAdd(&scur[e], 1);
    slot_of_pos[p] = s;
    pos_of_slot[s] = p;
  }
  if (t < NEXP) { counts[t] = sc[t]; offsets[t] = so[t]; }
}

// ---------------- fp32 -> bf16 conversion, all three tensors in one launch ----------------
__global__ void k_cvt3(const float* __restrict__ s0, const float* __restrict__ s1,
                       const float* __restrict__ s2, unsigned short* __restrict__ d0,
                       unsigned short* __restrict__ d1, unsigned short* __restrict__ d2,
                       int n0, int n1, int n2) {
  int stride = gridDim.x * blockDim.x;
  int tot = n0 + n1 + n2;
  for (int i = blockIdx.x * blockDim.x + threadIdx.x; i < tot; i += stride) {
    const float* s; unsigned short* d; int j;
    if (i < n0)            { s = s0; d = d0; j = i; }
    else if (i < n0 + n1)  { s = s1; d = d1; j = i - n0; }
    else                   { s = s2; d = d2; j = i - n0 - n1; }
    float4 a = ((const float4*)s)[2 * j];
    float4 b = ((const float4*)s)[2 * j + 1];
    union { unsigned short u[8]; uint4 v; } o;
    o.u[0] = f2bf(a.x); o.u[1] = f2bf(a.y); o.u[2] = f2bf(a.z); o.u[3] = f2bf(a.w);
    o.u[4] = f2bf(b.x); o.u[5] = f2bf(b.y); o.u[6] = f2bf(b.z); o.u[7] = f2bf(b.w);
    ((uint4*)d)[j] = o.v;
  }
}

// ---------------- grouped GEMM (NT): C[r, c] = A[r, :K] . B[c, :K] ----------------
// 128x128 tile, BK=64, 4 waves, each wave 64x64 (4x4 frags of 16x16x32 bf16).
// LDS XOR-swizzled byte^((row&7)<<4), staged via global_load_lds with the inverse
// swizzle applied to the GLOBAL source (rule #21). launch_bounds(256,4): 4 blocks/CU
// (LDS 4x32KB=128KB <= 160KB; acc lives in AGPRs so VGPR stays ~60).
template<int K, int NCOLS, bool GATHER, bool RELU2>
__global__ __launch_bounds__(256, 4)
void k_gemm(const unsigned short* __restrict__ A,
            const unsigned short* __restrict__ B,
            unsigned short* __restrict__ C,
            const int* __restrict__ counts,
            const int* __restrict__ offsets,
            const int* __restrict__ slot_of_pos)
{
  const int e   = blockIdx.z;
  const int cnt = counts[e];
  const int rt  = blockIdx.y;
  if (rt * 128 >= cnt) return;
  const int ct  = blockIdx.x;
  const int off = offsets[e];

  __shared__ unsigned short ldsA[128 * 64];
  __shared__ unsigned short ldsB[128 * 64];

  const int t    = threadIdx.x;
  const int lane = t & 63;
  const int wid  = t >> 6;

  const unsigned short* Bexp = B + (size_t)e * NCOLS * K;

  const unsigned short* aSrc[4];
  const unsigned short* bSrc[4];
  unsigned short* aDst[4];
  unsigned short* bDst[4];
#pragma unroll
  for (int j = 0; j < 4; ++j) {
    const int chunk = j * 4 + wid;                 // 0..15 (wave-uniform per call)
    const int row   = chunk * 8 + (lane >> 3);     // LDS row 0..127
    const int qcol  = ((lane & 7) * 16) ^ ((row & 7) << 4);  // pre-swizzled logical byte
    int pr  = rt * 128 + row;
    int prc = pr < cnt ? pr : 0;
    if constexpr (GATHER) {
      int tok = slot_of_pos[off + prc] >> 1;       // slot -> token (K=2)
      aSrc[j] = A + (size_t)tok * K + (qcol >> 1);
    } else {
      aSrc[j] = A + (size_t)(off + prc) * K + (qcol >> 1);
    }
    bSrc[j] = Bexp + (size_t)(ct * 128 + row) * K + (qcol >> 1);
    aDst[j] = ldsA + chunk * 512;
    bDst[j] = ldsB + chunk * 512;
  }

  f32x4 acc[4][4];
#pragma unroll
  for (int m = 0; m < 4; ++m)
#pragma unroll
    for (int n = 0; n < 4; ++n) acc[m][n] = (f32x4){0.f, 0.f, 0.f, 0.f};

  const int wr = wid >> 1, wc = wid & 1;
  const int kq = (lane >> 4) * 16;
  int aByte[4], bByte[4], aXor[4], bXor[4];
#pragma unroll
  for (int m = 0; m < 4; ++m) {
    int row = wr * 64 + m * 16 + (lane & 15);
    aByte[m] = row * 128; aXor[m] = (row & 7) << 4;
    int col = wc * 64 + m * 16 + (lane & 15);
    bByte[m] = col * 128; bXor[m] = (col & 7) << 4;
  }

  for (int kt = 0; kt < K / 64; ++kt) {
#pragma unroll
    for (int j = 0; j < 4; ++j) {
      GLD16(aSrc[j] + kt * 64, aDst[j]);
      GLD16(bSrc[j] + kt * 64, bDst[j]);
    }
    __syncthreads();
#pragma unroll
    for (int ks = 0; ks < 2; ++ks) {
      b16x8 af[4], bfr[4];
#pragma unroll
      for (int m = 0; m < 4; ++m) {
        af[m]  = *(const b16x8*)((const char*)ldsA + aByte[m] + (((ks * 64) + kq) ^ aXor[m]));
        bfr[m] = *(const b16x8*)((const char*)ldsB + bByte[m] + (((ks * 64) + kq) ^ bXor[m]));
      }
#pragma unroll
      for (int m = 0; m < 4; ++m)
#pragma unroll
        for (int n = 0; n < 4; ++n)
          acc[m][n] = __builtin_amdgcn_mfma_f32_16x16x32_bf16(af[m], bfr[n], acc[m][n], 0, 0, 0);
    }
    __syncthreads();
  }

  // epilogue: C/D layout col = lane&15, row = (lane>>4)*4 + r  (m89-verified)
  const int rbase = rt * 128 + wr * 64 + (lane >> 4) * 4;
  const int cbase = ct * 128 + wc * 64 + (lane & 15);
#pragma unroll
  for (int m = 0; m < 4; ++m) {
#pragma unroll
    for (int r = 0; r < 4; ++r) {
      int pr = rbase + m * 16 + r;
      if (pr < cnt) {
        unsigned short* crow = C + (size_t)(off + pr) * NCOLS + cbase;
#pragma unroll
        for (int n = 0; n < 4; ++n) {
          float v = acc[m][n][r];
          if (RELU2) v = v > 0.f ? v * v : 0.f;
          crow[n * 16] = f2bf(v);
        }
      }
    }
  }
}

// ---------------- weighted combine of the two slots per token ----------------
__global__ void k_combine(const unsigned short* __restrict__ oslt,
                          const int* __restrict__ pos_of_slot,
                          const float* __restrict__ ew,
                          float* __restrict__ out)
{
  int n = blockIdx.x;
  int d = threadIdx.x * 4;
  int p0 = pos_of_slot[2 * n];
  int p1 = pos_of_slot[2 * n + 1];
  float w0 = ew[2 * n], w1 = ew[2 * n + 1];
  ushort4 a = *(const ushort4*)(oslt + (size_t)p0 * DDIM + d);
  ushort4 b = *(const ushort4*)(oslt + (size_t)p1 * DDIM + d);
  float4 o;
  o.x = w0 * bf2f(a.x) + w1 * bf2f(b.x);
  o.y = w0 * bf2f(a.y) + w1 * bf2f(b.y);
  o.z = w0 * bf2f(a.z) + w1 * bf2f(b.z);
  o.w = w0 * bf2f(a.w) + w1 * bf2f(b.w);
  *(float4*)(out + (size_t)n * DDIM + d) = o;
}

extern "C" void kernel_launch(void* const* d_in, const int* in_sizes, int n_in,
                              void* d_out, int out_size, void* d_ws, size_t ws_size,
                              hipStream_t stream)
{
  const float* x  = (const float*)d_in[0];
  const int* eidx = (const int*)d_in[1];
  const float* ew = (const float*)d_in[2];
  const float* w1 = (const float*)d_in[3];
  const float* w2 = (const float*)d_in[4];
  float* out = (float*)d_out;

  char* ws = (char*)d_ws;
  // layout (bytes):
  //   [0,            16777216)  xb   (8192x1024 bf16)          } dead after up-GEMM
  //   [16777216,     50331648)  w1b  (8x2048x1024 bf16)        }
  //   [0,            33554432)  oslt (16384x1024 bf16)  -- aliases xb+w1b, live after up-GEMM
  //   [50331648,     83886080)  w2b  (8x1024x2048 bf16)
  //   [83886080,    150994944)  hid  (16384x2048 bf16)
  //   [150994944,  ...       )  routing ints
  unsigned short* xb   = (unsigned short*)ws;
  unsigned short* w1b  = (unsigned short*)(ws + (size_t)16777216);
  unsigned short* oslt = (unsigned short*)ws;
  unsigned short* w2b  = (unsigned short*)(ws + (size_t)50331648);
  unsigned short* hid  = (unsigned short*)(ws + (size_t)83886080);
  int* counts      = (int*)(ws + (size_t)150994944);
  int* offsets     = counts + NEXP;
  int* slot_of_pos = offsets + NEXP;
  int* pos_of_slot = slot_of_pos + NSLOTS;

  k_route<<<1, 1024, 0, stream>>>(eidx, counts, offsets, slot_of_pos, pos_of_slot);

  k_cvt3<<<2048, 256, 0, stream>>>(x, w1, w2, xb, w1b, w2b,
                                   N_TOK * DDIM / 8, NEXP * HDIM * DDIM / 8, NEXP * DDIM * HDIM / 8);

  dim3 gup(HDIM / 128, 128, NEXP);
  k_gemm<DDIM, HDIM, true,  true ><<<gup, 256, 0, stream>>>(xb,  w1b, hid,  counts, offsets, slot_of_pos);
  dim3 gdn(DDIM / 128, 128, NEXP);
  k_gemm<HDIM, DDIM, false, false><<<gdn, 256, 0, stream>>>(hid, w2b, oslt, counts, offsets, slot_of_pos);

  k_combine<<<N_TOK, 256, 0, stream>>>(oslt, pos_of_slot, ew, out);
}